// Round 1
// baseline (3319.392 us; speedup 1.0000x reference)
//
#include <hip/hip_runtime.h>
#include <hip/hip_bf16.h>

#define LL 12
#define BB 8
#define HH 12
#define EE 768
#define DD 64
#define SS 1024
#define VV 50257
#define E3 2304
#define E4 3072

__device__ __forceinline__ float gelu_tanh(float v) {
    float c = 0.7978845608028654f * (v + 0.044715f * v * v * v);
    return 0.5f * v * (1.0f + tanhf(c));
}

// h[b][e] = wte[ids[b]][e] + wpe[pos][e]
__global__ void k_embed(const int* __restrict__ ids, const int* __restrict__ posp,
                        const float* __restrict__ wte, const float* __restrict__ wpe,
                        float* __restrict__ h) {
    int i = blockIdx.x * 256 + threadIdx.x;
    if (i >= BB * EE) return;
    int b = i / EE, e = i % EE;
    h[i] = wte[(size_t)ids[b] * EE + e] + wpe[(size_t)(*posp) * EE + e];
}

// blocks [0,B): h += res (optional, in place), x = layernorm(h)*g+b
// blocks [B,B+N1): ib1[i] = bb1[i % C1]   (bias init slot 1)
// blocks [B+N1,...): ib2[i] = bb2[i % C2] (bias init slot 2)
__global__ void k_ln(float* __restrict__ h, const float* __restrict__ res,
                     const float* __restrict__ g, const float* __restrict__ bta,
                     float* __restrict__ x,
                     float* ib1, const float* bb1, int C1, int N1,
                     float* ib2, const float* bb2, int C2, int N2) {
    if ((int)blockIdx.x >= BB) {
        int ib = blockIdx.x - BB;
        if (ib < N1) {
            int i = ib * 256 + threadIdx.x;
            ib1[i] = bb1[i % C1];
        } else {
            int i = (ib - N1) * 256 + threadIdx.x;
            ib2[i] = bb2[i % C2];
        }
        return;
    }
    int b = blockIdx.x, tid = threadIdx.x;
    __shared__ float red[256];
    __shared__ float bc[2];
    float v0[3];
    float sum = 0.f;
#pragma unroll
    for (int i = 0; i < 3; i++) {
        int e = tid + i * 256;
        float hv = h[b * EE + e];
        if (res) { hv += res[b * EE + e]; h[b * EE + e] = hv; }
        v0[i] = hv; sum += hv;
    }
    red[tid] = sum; __syncthreads();
    for (int st = 128; st > 0; st >>= 1) { if (tid < st) red[tid] += red[tid + st]; __syncthreads(); }
    if (tid == 0) bc[0] = red[0] * (1.0f / EE);
    __syncthreads();
    float m = bc[0], s2 = 0.f;
#pragma unroll
    for (int i = 0; i < 3; i++) { float dv = v0[i] - m; s2 += dv * dv; }
    __syncthreads();
    red[tid] = s2; __syncthreads();
    for (int st = 128; st > 0; st >>= 1) { if (tid < st) red[tid] += red[tid + st]; __syncthreads(); }
    if (tid == 0) bc[1] = rsqrtf(red[0] * (1.0f / EE) + 1e-5f);
    __syncthreads();
    float r = bc[1];
#pragma unroll
    for (int i = 0; i < 3; i++) {
        int e = tid + i * 256;
        x[b * EE + e] = (v0[i] - m) * r * g[e] + bta[e];
    }
}

// out[b][c] += sum_{e in chunk} x[b][e] * W[e][c]   (atomic accumulate; out pre-init with bias)
// grid = nChunk * nColBlk, blockDim = 256. W row-major (EROWS x C).
template <bool GELU>
__global__ void k_gemm(const float* __restrict__ x, const float* __restrict__ W,
                       float* __restrict__ out, int C, int nColBlk, int EROWS) {
    __shared__ float xl[8][64];
    int colblk = blockIdx.x % nColBlk;
    int chunk = blockIdx.x / nColBlk;
    int e0 = chunk * 64;
    for (int i = threadIdx.x; i < 512; i += 256) {
        int b = i >> 6, e = i & 63;
        float v = x[(size_t)b * EROWS + e0 + e];
        if (GELU) v = gelu_tanh(v);
        xl[b][e] = v;
    }
    __syncthreads();
    int c = colblk * 256 + threadIdx.x;
    if (c >= C) return;
    const float* Wp = W + (size_t)e0 * C + c;
    float acc[8] = {0, 0, 0, 0, 0, 0, 0, 0};
#pragma unroll 8
    for (int e = 0; e < 64; e++) {
        float w = Wp[(size_t)e * C];
#pragma unroll
        for (int b = 0; b < 8; b++) acc[b] += xl[b][e] * w;
    }
#pragma unroll
    for (int b = 0; b < 8; b++) atomicAdd(&out[(size_t)b * C + c], acc[b]);
}

// Fused: attention for one (b,h) + full K/V cache copy-through (with new row at pos)
// blocks [0, B*H): attention; blocks >= B*H: init tproj with proj bias
__global__ void k_attn(const float* __restrict__ pk, const float* __restrict__ pv,
                       float* __restrict__ ok, float* __restrict__ ov,
                       const float* __restrict__ qkv, float* __restrict__ o,
                       float* __restrict__ tproj, const float* __restrict__ pbias,
                       const int* __restrict__ posp) {
    if ((int)blockIdx.x >= BB * HH) {
        int i = (blockIdx.x - BB * HH) * 256 + threadIdx.x;
        if (i < BB * EE) tproj[i] = pbias[i % EE];
        return;
    }
    int b = blockIdx.x / HH, hh = blockIdx.x % HH;
    int pos = *posp;
    int kv = pos + 1;
    const size_t off = ((size_t)b * HH + hh) * SS * DD;
    const float* Kc = pk + off;
    const float* Vc = pv + off;
    float* Ko = ok + off;
    float* Vo = ov + off;
    const float* qn = qkv + (size_t)b * E3 + hh * DD;
    const float* kn = qn + EE;
    const float* vn = qn + 2 * EE;

    __shared__ float s[SS];
    __shared__ float qs[DD];
    __shared__ float red[256];
    __shared__ float bc[2];
    int tid = threadIdx.x;
    if (tid < DD) qs[tid] = qn[tid];
    __syncthreads();

    // pass 1: stream K rows: copy out (new k at pos) + dot with q
    for (int j = tid; j < SS; j += 256) {
        const float4* src = (const float4*)((j == pos) ? kn : (Kc + (size_t)j * DD));
        float4* dst = (float4*)(Ko + (size_t)j * DD);
        float sj = 0.f;
#pragma unroll
        for (int i = 0; i < 16; i++) {
            float4 kx = src[i];
            dst[i] = kx;
            sj += kx.x * qs[4 * i] + kx.y * qs[4 * i + 1] + kx.z * qs[4 * i + 2] + kx.w * qs[4 * i + 3];
        }
        if (j < kv) s[j] = sj * 0.125f;  // 1/sqrt(64)
    }
    __syncthreads();

    // softmax over s[0..kv)
    float mx = -1e30f;
    for (int j = tid; j < kv; j += 256) mx = fmaxf(mx, s[j]);
    red[tid] = mx; __syncthreads();
    for (int st = 128; st > 0; st >>= 1) { if (tid < st) red[tid] = fmaxf(red[tid], red[tid + st]); __syncthreads(); }
    if (tid == 0) bc[0] = red[0];
    __syncthreads();
    mx = bc[0];
    float sum = 0.f;
    for (int j = tid; j < kv; j += 256) { float p = __expf(s[j] - mx); s[j] = p; sum += p; }
    __syncthreads();
    red[tid] = sum; __syncthreads();
    for (int st = 128; st > 0; st >>= 1) { if (tid < st) red[tid] += red[tid + st]; __syncthreads(); }
    if (tid == 0) bc[1] = 1.0f / red[0];
    __syncthreads();
    float inv = bc[1];

    // pass 2: stream V rows: copy out (new v at pos) + weighted accumulate
    int d = tid & 63, grp = tid >> 6;
    float od = 0.f;
    for (int j = grp; j < SS; j += 4) {
        float vv = (j == pos) ? vn[d] : Vc[(size_t)j * DD + d];
        Vo[(size_t)j * DD + d] = vv;
        if (j < kv) od += s[j] * vv;
    }
    __syncthreads();
    red[tid] = od; __syncthreads();
    if (tid < 64) {
        float t = red[tid] + red[64 + tid] + red[128 + tid] + red[192 + tid];
        o[(size_t)b * EE + hh * DD + tid] = t * inv;
    }
}

// logits[b][v] = dot(x[b,:], wte[v,:]) ; 64 v per block, 4 lanes split E
__global__ void k_logits(const float* __restrict__ x, const float* __restrict__ wte,
                         float* __restrict__ logits) {
    __shared__ float xl[8][768];
    for (int i = threadIdx.x; i < 8 * 768; i += 256) xl[i / 768][i % 768] = x[i];
    __syncthreads();
    int t = threadIdx.x;
    int v = blockIdx.x * 64 + (t >> 2);
    if (v >= VV) return;
    int el = t & 3;
    const float4* w = (const float4*)(wte + (size_t)v * EE);
    float acc[8] = {0, 0, 0, 0, 0, 0, 0, 0};
    for (int i = el; i < 192; i += 4) {
        float4 w4 = w[i];
#pragma unroll
        for (int b = 0; b < 8; b++) {
            float4 xx = ((const float4*)xl[b])[i];
            acc[b] += w4.x * xx.x + w4.y * xx.y + w4.z * xx.z + w4.w * xx.w;
        }
    }
#pragma unroll
    for (int b = 0; b < 8; b++) {
        acc[b] += __shfl_xor(acc[b], 1);
        acc[b] += __shfl_xor(acc[b], 2);
    }
    if (el == 0) {
#pragma unroll
        for (int b = 0; b < 8; b++) logits[(size_t)b * VV + v] = acc[b];
    }
}

extern "C" void kernel_launch(void* const* d_in, const int* in_sizes, int n_in,
                              void* d_out, int out_size, void* d_ws, size_t ws_size,
                              hipStream_t stream) {
    const int* ids = (const int*)d_in[0];
    const int* posp = (const int*)d_in[1];
    const float* past_k = (const float*)d_in[2];
    const float* past_v = (const float*)d_in[3];
    const float* wte = (const float*)d_in[4];
    const float* wpe = (const float*)d_in[5];
    const float* ln1g = (const float*)d_in[6];
    const float* ln1b = (const float*)d_in[7];
    const float* aw = (const float*)d_in[8];
    const float* ab = (const float*)d_in[9];
    const float* pw = (const float*)d_in[10];
    const float* pb = (const float*)d_in[11];
    const float* ln2g = (const float*)d_in[12];
    const float* ln2b = (const float*)d_in[13];
    const float* fw = (const float*)d_in[14];
    const float* fb = (const float*)d_in[15];
    const float* fpw = (const float*)d_in[16];
    const float* fpb = (const float*)d_in[17];
    const float* lnfg = (const float*)d_in[18];
    const float* lnfb = (const float*)d_in[19];

    float* logits = (float*)d_out;
    float* okeys = logits + (size_t)BB * VV;
    float* ovals = okeys + (size_t)LL * BB * HH * SS * DD;

    float* ws = (float*)d_ws;
    float* h = ws;                  // B*E
    float* x = h + BB * EE;         // B*E
    float* qkv = x + BB * EE;       // B*3E
    float* o = qkv + BB * E3;       // B*E
    float* tproj = o + BB * EE;     // B*E
    float* tmlp = tproj + BB * EE;  // B*E
    float* fcbuf = tmlp + BB * EE;  // B*4E

    k_embed<<<24, 256, 0, stream>>>(ids, posp, wte, wpe, h);

    const float* res = nullptr;
    for (int l = 0; l < LL; l++) {
        size_t co = (size_t)l * BB * HH * SS * DD;
        // ln1 (+ residual from previous layer's MLP) + init qkv with attn bias
        k_ln<<<8 + 72, 256, 0, stream>>>(h, res, ln1g + l * EE, ln1b + l * EE, x,
                                         qkv, ab + (size_t)l * E3, E3, 72,
                                         nullptr, nullptr, 0, 0);
        // qkv = x @ attn_w + bias
        k_gemm<false><<<12 * 9, 256, 0, stream>>>(x, aw + (size_t)l * EE * E3, qkv, E3, 9, EE);
        // attention + full KV cache copy-through; init tproj with proj bias
        k_attn<<<96 + 24, 256, 0, stream>>>(past_k + co, past_v + co, okeys + co, ovals + co,
                                            qkv, o, tproj, pb + (size_t)l * EE, posp);
        // tproj += o @ proj_w
        k_gemm<false><<<12 * 3, 256, 0, stream>>>(o, pw + (size_t)l * EE * EE, tproj, EE, 3, EE);
        // h += tproj; x = ln2(h); init fcbuf with fc bias; init tmlp with fcp bias
        k_ln<<<8 + 96 + 24, 256, 0, stream>>>(h, tproj, ln2g + l * EE, ln2b + l * EE, x,
                                              fcbuf, fb + (size_t)l * E4, E4, 96,
                                              tmlp, fpb + (size_t)l * EE, EE, 24);
        // fcbuf += x @ fc_w
        k_gemm<false><<<12 * 12, 256, 0, stream>>>(x, fw + (size_t)l * EE * E4, fcbuf, E4, 12, EE);
        // tmlp += gelu(fcbuf) @ fcp_w
        k_gemm<true><<<48 * 3, 256, 0, stream>>>(fcbuf, fpw + (size_t)l * E4 * EE, tmlp, EE, 3, E4);
        res = tmlp;
    }
    // h += last MLP; x = lnf(h)
    k_ln<<<8, 256, 0, stream>>>(h, res, lnfg, lnfb, x,
                                nullptr, nullptr, 0, 0, nullptr, nullptr, 0, 0);
    // logits = x @ wte^T
    k_logits<<<(VV + 63) / 64, 256, 0, stream>>>(x, wte, logits);
}

// Round 2
// 1815.585 us; speedup vs baseline: 1.8283x; 1.8283x over previous
//
#include <hip/hip_runtime.h>
#include <hip/hip_bf16.h>

#define LL 12
#define BB 8
#define HH 12
#define EE 768
#define DD 64
#define SS 1024
#define VV 50257
#define E3 2304
#define E4 3072
#define NCH 4   // attention row-chunks per (b,h): 1024/256

__device__ __forceinline__ float gelu_tanh(float v) {
    float c = 0.7978845608028654f * (v + 0.044715f * v * v * v);
    return 0.5f * v * (1.0f + tanhf(c));
}

// h[b][e] = wte[ids[b]][e] + wpe[pos][e]
__global__ void k_embed(const int* __restrict__ ids, const int* __restrict__ posp,
                        const float* __restrict__ wte, const float* __restrict__ wpe,
                        float* __restrict__ h) {
    int i = blockIdx.x * 256 + threadIdx.x;
    if (i >= BB * EE) return;
    int b = i / EE, e = i % EE;
    h[i] = wte[(size_t)ids[b] * EE + e] + wpe[(size_t)(*posp) * EE + e];
}

// blocks [0,B): h += res (optional, in place), x = layernorm(h)*g+b
// blocks [B,B+N1): ib1 = bias bb1 broadcast; blocks beyond: ib2 = bb2 broadcast
__global__ void k_ln(float* __restrict__ h, const float* __restrict__ res,
                     const float* __restrict__ g, const float* __restrict__ bta,
                     float* __restrict__ x,
                     float* ib1, const float* bb1, int C1, int N1,
                     float* ib2, const float* bb2, int C2, int N2) {
    if ((int)blockIdx.x >= BB) {
        int ib = blockIdx.x - BB;
        if (ib < N1) {
            int i = ib * 256 + threadIdx.x;
            ib1[i] = bb1[i % C1];
        } else {
            int i = (ib - N1) * 256 + threadIdx.x;
            ib2[i] = bb2[i % C2];
        }
        return;
    }
    int b = blockIdx.x, tid = threadIdx.x;
    __shared__ float red[256];
    __shared__ float bc[2];
    float v0[3];
    float sum = 0.f;
#pragma unroll
    for (int i = 0; i < 3; i++) {
        int e = tid + i * 256;
        float hv = h[b * EE + e];
        if (res) { hv += res[b * EE + e]; h[b * EE + e] = hv; }
        v0[i] = hv; sum += hv;
    }
    red[tid] = sum; __syncthreads();
    for (int st = 128; st > 0; st >>= 1) { if (tid < st) red[tid] += red[tid + st]; __syncthreads(); }
    if (tid == 0) bc[0] = red[0] * (1.0f / EE);
    __syncthreads();
    float m = bc[0], s2 = 0.f;
#pragma unroll
    for (int i = 0; i < 3; i++) { float dv = v0[i] - m; s2 += dv * dv; }
    __syncthreads();
    red[tid] = s2; __syncthreads();
    for (int st = 128; st > 0; st >>= 1) { if (tid < st) red[tid] += red[tid + st]; __syncthreads(); }
    if (tid == 0) bc[1] = rsqrtf(red[0] * (1.0f / EE) + 1e-5f);
    __syncthreads();
    float r = bc[1];
#pragma unroll
    for (int i = 0; i < 3; i++) {
        int e = tid + i * 256;
        x[b * EE + e] = (v0[i] - m) * r * g[e] + bta[e];
    }
}

// out[b][c] += sum_{e in K-chunk of 32} x[b][e] * W[e][c]  (atomic; out pre-init with bias)
template <bool GELU>
__global__ void k_gemm(const float* __restrict__ x, const float* __restrict__ W,
                       float* __restrict__ out, int C, int nColBlk, int EROWS) {
    __shared__ float xl[8][32];
    int colblk = blockIdx.x % nColBlk;
    int chunk = blockIdx.x / nColBlk;
    int e0 = chunk * 32;
    {
        int b = threadIdx.x >> 5, e = threadIdx.x & 31;
        float v = x[(size_t)b * EROWS + e0 + e];
        if (GELU) v = gelu_tanh(v);
        xl[b][e] = v;
    }
    __syncthreads();
    int c = colblk * 256 + threadIdx.x;
    if (c >= C) return;
    const float* Wp = W + (size_t)e0 * C + c;
    float acc[8] = {0, 0, 0, 0, 0, 0, 0, 0};
#pragma unroll 8
    for (int e = 0; e < 32; e++) {
        float w = Wp[(size_t)e * C];
#pragma unroll
        for (int b = 0; b < 8; b++) acc[b] += xl[b][e] * w;
    }
#pragma unroll
    for (int b = 0; b < 8; b++) atomicAdd(&out[(size_t)b * C + c], acc[b]);
}

// Fused flash-decode attention chunk + K/V cache copy-through.
// grid = B*H*NCH. Block (bh,ch) copies rows [ch*256, ch*256+256) of K and V
// (substituting the new row at pos), and produces partial softmax (m, sum, o[64]).
__global__ void k_attn(const float* __restrict__ pk, const float* __restrict__ pv,
                       float* __restrict__ ok, float* __restrict__ ov,
                       const float* __restrict__ qkv,
                       float* __restrict__ pm, float* __restrict__ psum,
                       float* __restrict__ po, const int* __restrict__ posp) {
    int blk = blockIdx.x;
    int ch = blk & (NCH - 1);
    int bh = blk >> 2;
    int b = bh / HH, hh = bh % HH;
    int pos = *posp;
    int kv = pos + 1;
    int j0 = ch * 256;
    const size_t off = (size_t)bh * SS * DD;
    const float* Kc = pk + off;
    const float* Vc = pv + off;
    float* Ko = ok + off;
    float* Vo = ov + off;
    const float* qn = qkv + (size_t)b * E3 + hh * DD;
    const float* kn = qn + EE;
    const float* vn = qn + 2 * EE;

    __shared__ float s[256];
    __shared__ float qs[DD];
    __shared__ float red[256];
    __shared__ float bc[2];
    int tid = threadIdx.x;
    bool active = (j0 < kv);
    if (active && tid < DD) qs[tid] = qn[tid];
    __syncthreads();

    // pass 1: copy K rows (one row per thread) + dot with q
    int j = j0 + tid;
    {
        const float4* src = (const float4*)((j == pos) ? kn : (Kc + (size_t)j * DD));
        float4* dst = (float4*)(Ko + (size_t)j * DD);
        float sj = 0.f;
#pragma unroll
        for (int i = 0; i < 16; i++) {
            float4 kx = src[i];
            dst[i] = kx;
            if (active) sj += kx.x * qs[4 * i] + kx.y * qs[4 * i + 1] + kx.z * qs[4 * i + 2] + kx.w * qs[4 * i + 3];
        }
        s[tid] = (active && j < kv) ? sj * 0.125f : -INFINITY;
    }
    __syncthreads();

    float m = -INFINITY, inv_unused = 0.f;
    (void)inv_unused;
    if (active) {
        red[tid] = s[tid]; __syncthreads();
        for (int st = 128; st > 0; st >>= 1) { if (tid < st) red[tid] = fmaxf(red[tid], red[tid + st]); __syncthreads(); }
        if (tid == 0) bc[0] = red[0];
        __syncthreads();
        m = bc[0];
        float p = __expf(s[tid] - m);
        s[tid] = p;
        __syncthreads();
        red[tid] = p; __syncthreads();
        for (int st = 128; st > 0; st >>= 1) { if (tid < st) red[tid] += red[tid + st]; __syncthreads(); }
        if (tid == 0) bc[1] = red[0];
        __syncthreads();
    }

    // pass 2: copy V rows + weighted accumulate (p from s[])
    int d = tid & 63, grp = tid >> 6;
    float od = 0.f;
    for (int jj = j0 + grp; jj < j0 + 256; jj += 4) {
        float vv = (jj == pos) ? vn[d] : Vc[(size_t)jj * DD + d];
        Vo[(size_t)jj * DD + d] = vv;
        if (active && jj < kv) od += s[jj - j0] * vv;
    }
    if (active) {
        __syncthreads();
        red[tid] = od; __syncthreads();
        int idx = bh * NCH + ch;
        if (tid < 64) {
            float t = red[tid] + red[64 + tid] + red[128 + tid] + red[192 + tid];
            po[(size_t)idx * 64 + tid] = t;
        }
        if (tid == 0) { pm[idx] = m; psum[idx] = bc[1]; }
    } else if (tid == 0) {
        psum[bh * NCH + ch] = 0.f;
    }
}

// Combine attention partials -> o[b][h*64+d]. Extra blocks init tproj with proj bias.
__global__ void k_comb(const float* __restrict__ pm, const float* __restrict__ psum,
                       const float* __restrict__ po, float* __restrict__ o,
                       float* __restrict__ tproj, const float* __restrict__ pbias) {
    if ((int)blockIdx.x >= BB * HH) {
        int i = (blockIdx.x - BB * HH) * 256 + threadIdx.x;
        if (i < BB * EE) tproj[i] = pbias[i % EE];
        return;
    }
    int bh = blockIdx.x;
    int b = bh / HH, hh = bh % HH;
    int tid = threadIdx.x;
    if (tid >= 64) return;
    float M = -INFINITY;
#pragma unroll
    for (int ch = 0; ch < NCH; ch++) {
        int idx = bh * NCH + ch;
        if (psum[idx] > 0.f) M = fmaxf(M, pm[idx]);
    }
    float den = 0.f, acc = 0.f;
#pragma unroll
    for (int ch = 0; ch < NCH; ch++) {
        int idx = bh * NCH + ch;
        float ps = psum[idx];
        if (ps > 0.f) {
            float f = __expf(pm[idx] - M);
            den += ps * f;
            acc += po[(size_t)idx * 64 + tid] * f;
        }
    }
    o[(size_t)b * EE + hh * DD + tid] = acc / den;
}

// logits[b][v] = dot(x[b,:], wte[v,:]) ; 64 v per block, 4 lanes split E
__global__ void k_logits(const float* __restrict__ x, const float* __restrict__ wte,
                         float* __restrict__ logits) {
    __shared__ float xl[8][768];
    for (int i = threadIdx.x; i < 8 * 768; i += 256) xl[i / 768][i % 768] = x[i];
    __syncthreads();
    int t = threadIdx.x;
    int v = blockIdx.x * 64 + (t >> 2);
    if (v >= VV) return;
    int el = t & 3;
    const float4* w = (const float4*)(wte + (size_t)v * EE);
    float acc[8] = {0, 0, 0, 0, 0, 0, 0, 0};
    for (int i = el; i < 192; i += 4) {
        float4 w4 = w[i];
#pragma unroll
        for (int b = 0; b < 8; b++) {
            float4 xx = ((const float4*)xl[b])[i];
            acc[b] += w4.x * xx.x + w4.y * xx.y + w4.z * xx.z + w4.w * xx.w;
        }
    }
#pragma unroll
    for (int b = 0; b < 8; b++) {
        acc[b] += __shfl_xor(acc[b], 1);
        acc[b] += __shfl_xor(acc[b], 2);
    }
    if (el == 0) {
#pragma unroll
        for (int b = 0; b < 8; b++) logits[(size_t)b * VV + v] = acc[b];
    }
}

extern "C" void kernel_launch(void* const* d_in, const int* in_sizes, int n_in,
                              void* d_out, int out_size, void* d_ws, size_t ws_size,
                              hipStream_t stream) {
    const int* ids = (const int*)d_in[0];
    const int* posp = (const int*)d_in[1];
    const float* past_k = (const float*)d_in[2];
    const float* past_v = (const float*)d_in[3];
    const float* wte = (const float*)d_in[4];
    const float* wpe = (const float*)d_in[5];
    const float* ln1g = (const float*)d_in[6];
    const float* ln1b = (const float*)d_in[7];
    const float* aw = (const float*)d_in[8];
    const float* ab = (const float*)d_in[9];
    const float* pw = (const float*)d_in[10];
    const float* pb = (const float*)d_in[11];
    const float* ln2g = (const float*)d_in[12];
    const float* ln2b = (const float*)d_in[13];
    const float* fw = (const float*)d_in[14];
    const float* fb = (const float*)d_in[15];
    const float* fpw = (const float*)d_in[16];
    const float* fpb = (const float*)d_in[17];
    const float* lnfg = (const float*)d_in[18];
    const float* lnfb = (const float*)d_in[19];

    float* logits = (float*)d_out;
    float* okeys = logits + (size_t)BB * VV;
    float* ovals = okeys + (size_t)LL * BB * HH * SS * DD;

    float* ws = (float*)d_ws;
    float* h = ws;                  // B*E
    float* x = h + BB * EE;         // B*E
    float* qkv = x + BB * EE;       // B*3E
    float* o = qkv + BB * E3;       // B*E
    float* tproj = o + BB * EE;     // B*E
    float* tmlp = tproj + BB * EE;  // B*E
    float* fcbuf = tmlp + BB * EE;  // B*4E
    float* pm = fcbuf + BB * E4;    // 96*NCH
    float* psum = pm + BB * HH * NCH;
    float* po = psum + BB * HH * NCH;  // 96*NCH*64

    k_embed<<<24, 256, 0, stream>>>(ids, posp, wte, wpe, h);

    const float* res = nullptr;
    for (int l = 0; l < LL; l++) {
        size_t co = (size_t)l * BB * HH * SS * DD;
        // ln1 (+ residual) + init qkv with attn bias
        k_ln<<<8 + 72, 256, 0, stream>>>(h, res, ln1g + l * EE, ln1b + l * EE, x,
                                         qkv, ab + (size_t)l * E3, E3, 72,
                                         nullptr, nullptr, 0, 0);
        // qkv += x @ attn_w
        k_gemm<false><<<24 * 9, 256, 0, stream>>>(x, aw + (size_t)l * EE * E3, qkv, E3, 9, EE);
        // chunked attention + KV cache copy-through
        k_attn<<<BB * HH * NCH, 256, 0, stream>>>(past_k + co, past_v + co, okeys + co, ovals + co,
                                                  qkv, pm, psum, po, posp);
        // combine partials -> o ; init tproj with proj bias
        k_comb<<<96 + 24, 256, 0, stream>>>(pm, psum, po, o, tproj, pb + (size_t)l * EE);
        // tproj += o @ proj_w
        k_gemm<false><<<24 * 3, 256, 0, stream>>>(o, pw + (size_t)l * EE * EE, tproj, EE, 3, EE);
        // h += tproj; x = ln2(h); init fcbuf with fc bias; init tmlp with fcp bias
        k_ln<<<8 + 96 + 24, 256, 0, stream>>>(h, tproj, ln2g + l * EE, ln2b + l * EE, x,
                                              fcbuf, fb + (size_t)l * E4, E4, 96,
                                              tmlp, fpb + (size_t)l * EE, EE, 24);
        // fcbuf += x @ fc_w
        k_gemm<false><<<24 * 12, 256, 0, stream>>>(x, fw + (size_t)l * EE * E4, fcbuf, E4, 12, EE);
        // tmlp += gelu(fcbuf) @ fcp_w
        k_gemm<true><<<96 * 3, 256, 0, stream>>>(fcbuf, fpw + (size_t)l * E4 * EE, tmlp, EE, 3, E4);
        res = tmlp;
    }
    // h += last MLP; x = lnf(h)
    k_ln<<<8, 256, 0, stream>>>(h, res, lnfg, lnfb, x,
                                nullptr, nullptr, 0, 0, nullptr, nullptr, 0, 0);
    // logits = x @ wte^T
    k_logits<<<(VV + 63) / 64, 256, 0, stream>>>(x, wte, logits);
}

// Round 3
// 904.847 us; speedup vs baseline: 3.6685x; 2.0065x over previous
//
#include <hip/hip_runtime.h>
#include <hip/hip_bf16.h>

#define LL 12
#define BB 8
#define HH 12
#define EE 768
#define DD 64
#define SS 1024
#define VV 50257
#define E3 2304
#define E4 3072
#define NCH 8
#define CROWS 128  // KV rows per attention chunk

__device__ __forceinline__ float gelu_tanh(float v) {
    float c = 0.7978845608028654f * (v + 0.044715f * v * v * v);
    return 0.5f * v * (1.0f + tanhf(c));
}

// ---------------- bulk KV copy (full buffer; row pos overwritten later) ---------
__global__ void k_copy(const float4* __restrict__ src, float4* __restrict__ dst, size_t n4) {
    size_t i = (size_t)blockIdx.x * blockDim.x + threadIdx.x;
    size_t stride = (size_t)gridDim.x * blockDim.x;
    for (; i < n4; i += stride) dst[i] = src[i];
}

// ---------------- prologue: embed -> hB, tmlp=0, qkv=attn bias layer0 ----------
__global__ void k_pre(const int* __restrict__ ids, const int* __restrict__ posp,
                      const float* __restrict__ wte, const float* __restrict__ wpe,
                      float* __restrict__ hB, float* __restrict__ tmlp,
                      float* __restrict__ qkv, const float* __restrict__ ab0) {
    int blk = blockIdx.x, t = threadIdx.x;
    if (blk < 24) {
        int i = blk * 256 + t;
        int b = i / EE, e = i % EE;
        hB[i] = wte[(size_t)ids[b] * EE + e] + wpe[(size_t)(*posp) * EE + e];
    } else if (blk < 48) {
        int i = (blk - 24) * 256 + t;
        tmlp[i] = 0.f;
    } else {
        int i = (blk - 48) * 256 + t;
        qkv[i] = ab0[i % E3];
    }
}

// per-row LN stats over (h1+h2), 8 rows x 768, 32 threads/row
__device__ __forceinline__ void ln_stats(const float* __restrict__ h1, const float* __restrict__ h2,
                                         float* mean, float* rstd) {
    int t = threadIdx.x, r = t >> 5, l = t & 31;
    float s = 0.f, ss = 0.f;
#pragma unroll
    for (int i = 0; i < 24; i++) {
        int e = l + i * 32;
        float v = h1[r * EE + e] + h2[r * EE + e];
        s += v; ss += v * v;
    }
#pragma unroll
    for (int m = 16; m >= 1; m >>= 1) { s += __shfl_xor(s, m); ss += __shfl_xor(ss, m); }
    if (l == 0) {
        float mu = s * (1.f / EE);
        mean[r] = mu;
        rstd[r] = rsqrtf(ss * (1.f / EE) - mu * mu + 1e-5f);
    }
}

// inner GEMM: xl[8][32] (LDS) x W[32 x C-slice] -> atomicAdd out[8][64cols]
__device__ __forceinline__ void gemm_tile(const float (*xl)[32], const float* __restrict__ W,
                                          float* __restrict__ out, int e0, int c0, int C) {
    int t = threadIdx.x;
    int c = c0 + (t & 63);
    int r2 = (t >> 6) * 2;
    const float* Wp = W + (size_t)e0 * C + c;
    float a0 = 0.f, a1 = 0.f;
#pragma unroll
    for (int e = 0; e < 32; e++) {
        float w = Wp[(size_t)e * C];
        a0 += xl[r2][e] * w;
        a1 += xl[r2 + 1][e] * w;
    }
    atomicAdd(&out[(size_t)r2 * C + c], a0);
    atomicAdd(&out[(size_t)(r2 + 1) * C + c], a1);
}

// fused: x = LN(h1+h2); out += x @ W  (out pre-initialized with bias)
// extra blocks: [nGemm, nGemm+24): hWrite = h1+h2 ; beyond: ib = bias bb broadcast
__global__ void k_ln_gemm(const float* __restrict__ h1, const float* __restrict__ h2,
                          const float* __restrict__ g, const float* __restrict__ bt,
                          const float* __restrict__ W, float* __restrict__ out,
                          int C, int nColBlk,
                          float* __restrict__ hWrite,
                          float* __restrict__ ib, const float* __restrict__ bb, int bC) {
    int nGemm = 24 * nColBlk;
    int blk = blockIdx.x, t = threadIdx.x;
    if (blk >= nGemm) {
        int x = blk - nGemm;
        if (x < 24) { int i = x * 256 + t; hWrite[i] = h1[i] + h2[i]; }
        else { int i = (x - 24) * 256 + t; ib[i] = bb[i % bC]; }
        return;
    }
    int chunk = blk / nColBlk, colblk = blk % nColBlk;
    int e0 = chunk * 32, c0 = colblk * 64;
    __shared__ float xl[8][32];
    __shared__ float mean[8], rstd[8];
    ln_stats(h1, h2, mean, rstd);
    __syncthreads();
    {
        int b = t >> 5, l = t & 31, e = e0 + l;
        xl[b][l] = (h1[b * EE + e] + h2[b * EE + e] - mean[b]) * rstd[b] * g[e] + bt[e];
    }
    __syncthreads();
    gemm_tile(xl, W, out, e0, c0, C);
}

// lean flash-decode attention chunk (+ write new K/V row at pos to out cache)
// extra blocks init fcbuf with fc bias
__global__ void k_attn(const float* __restrict__ pk, const float* __restrict__ pv,
                       float* __restrict__ ok, float* __restrict__ ov,
                       const float* __restrict__ qkv,
                       float* __restrict__ pm, float* __restrict__ psum, float* __restrict__ po,
                       const int* __restrict__ posp,
                       float* __restrict__ ib, const float* __restrict__ bb) {
    int blk = blockIdx.x, t = threadIdx.x;
    if (blk >= BB * HH * NCH) {
        int i = (blk - BB * HH * NCH) * 256 + t;
        ib[i] = bb[i % E4];
        return;
    }
    int ch = blk & (NCH - 1), bh = blk >> 3;
    int b = bh / HH, hh = bh % HH;
    int pos = *posp, kv = pos + 1;
    int j0 = ch * CROWS;
    int idx = bh * NCH + ch;
    if (j0 >= kv) { if (t == 0) psum[idx] = 0.f; return; }

    const size_t off = (size_t)bh * SS * DD;
    const float* Kc = pk + off;
    const float* Vc = pv + off;
    const float* qn = qkv + (size_t)b * E3 + hh * DD;
    const float* kn = qn + EE;
    const float* vn = qn + 2 * EE;

    __shared__ float qs[DD], s[CROWS], red[256], bc[2];
    if (t < DD) qs[t] = qn[t];
    __syncthreads();

    // K pass: 2 threads per row (half-rows of 32 floats)
    int row = t >> 1, half = t & 1;
    int j = j0 + row;
    float sj = 0.f;
    if (j < kv) {
        const float4* s4 = (const float4*)(((j == pos) ? kn : (Kc + (size_t)j * DD)) + half * 32);
#pragma unroll
        for (int i = 0; i < 8; i++) {
            float4 k4 = s4[i];
            sj += k4.x * qs[half * 32 + 4 * i] + k4.y * qs[half * 32 + 4 * i + 1] +
                  k4.z * qs[half * 32 + 4 * i + 2] + k4.w * qs[half * 32 + 4 * i + 3];
        }
    }
    sj += __shfl_xor(sj, 1);
    if (j == pos) {  // write new K row to out cache
        float4* dst = (float4*)(ok + off + (size_t)pos * DD + half * 32);
        const float4* sn = (const float4*)(kn + half * 32);
#pragma unroll
        for (int i = 0; i < 8; i++) dst[i] = sn[i];
    }
    if (half == 0) s[row] = (j < kv) ? sj * 0.125f : -INFINITY;
    __syncthreads();

    // chunk max
    red[t] = (t < CROWS) ? s[t] : -INFINITY;
    __syncthreads();
    for (int st = 128; st >= 1; st >>= 1) { if (t < st) red[t] = fmaxf(red[t], red[t + st]); __syncthreads(); }
    if (t == 0) bc[0] = red[0];
    __syncthreads();
    float m = bc[0];
    if (t < CROWS) s[t] = __expf(s[t] - m);  // exp(-inf - m) = 0
    __syncthreads();
    red[t] = (t < CROWS) ? s[t] : 0.f;
    __syncthreads();
    for (int st = 128; st >= 1; st >>= 1) { if (t < st) red[t] += red[t + st]; __syncthreads(); }
    if (t == 0) bc[1] = red[0];

    // V pass
    int d = t & 63, grp = t >> 6;
    float od = 0.f;
    for (int jj = j0 + grp; jj < j0 + CROWS; jj += 4) {
        if (jj == pos) {
            float vv = vn[d];
            ov[off + (size_t)pos * DD + d] = vv;
            od += s[jj - j0] * vv;
        } else if (jj < kv) {
            od += s[jj - j0] * Vc[(size_t)jj * DD + d];
        }
    }
    __syncthreads();
    red[t] = od;
    __syncthreads();
    if (t < 64) {
        float tt = red[t] + red[64 + t] + red[128 + t] + red[192 + t];
        po[(size_t)idx * 64 + t] = tt;
    }
    if (t == 0) { pm[idx] = m; psum[idx] = bc[1]; }
}

// fused: o = combine(partials); tproj += o @ proj_w. extra blocks: tmlp = fcp bias
__global__ void k_comb_gemm(const float* __restrict__ pm, const float* __restrict__ psum,
                            const float* __restrict__ po,
                            const float* __restrict__ W, float* __restrict__ out,
                            float* __restrict__ ib, const float* __restrict__ bb) {
    const int nGemm = 24 * 12;
    int blk = blockIdx.x, t = threadIdx.x;
    if (blk >= nGemm) {
        int i = (blk - nGemm) * 256 + t;
        ib[i] = bb[i % EE];
        return;
    }
    int chunk = blk / 12, colblk = blk % 12;
    int e0 = chunk * 32, c0 = colblk * 64;
    __shared__ float xl[8][32];
    {
        int b = t >> 5, l = t & 31;
        int e = e0 + l;
        int hh = e >> 6, d = e & 63;
        int bh = b * HH + hh;
        float M = -INFINITY;
#pragma unroll
        for (int ch = 0; ch < NCH; ch++) {
            int idx = bh * NCH + ch;
            if (psum[idx] > 0.f) M = fmaxf(M, pm[idx]);
        }
        float den = 0.f, acc = 0.f;
#pragma unroll
        for (int ch = 0; ch < NCH; ch++) {
            int idx = bh * NCH + ch;
            float ps = psum[idx];
            if (ps > 0.f) {
                float f = __expf(pm[idx] - M);
                den += ps * f;
                acc += po[(size_t)idx * 64 + d] * f;
            }
        }
        xl[b][l] = acc / den;
    }
    __syncthreads();
    gemm_tile(xl, W, out, e0, c0, EE);
}

// fused: tmlp += gelu(fcbuf) @ fcp_w. extra blocks: qkv = next layer attn bias
__global__ void k_gelu_gemm(const float* __restrict__ fc, const float* __restrict__ W,
                            float* __restrict__ out,
                            float* __restrict__ ib, const float* __restrict__ bb) {
    const int nGemm = 96 * 12;
    int blk = blockIdx.x, t = threadIdx.x;
    if (blk >= nGemm) {
        int i = (blk - nGemm) * 256 + t;
        ib[i] = bb[i % E3];
        return;
    }
    int chunk = blk / 12, colblk = blk % 12;
    int e0 = chunk * 32, c0 = colblk * 64;
    __shared__ float xl[8][32];
    {
        int b = t >> 5, l = t & 31;
        xl[b][l] = gelu_tanh(fc[(size_t)b * E4 + e0 + l]);
    }
    __syncthreads();
    gemm_tile(xl, W, out, e0, c0, EE);
}

// fused final LN + logits = lnf(hB+tmlp) @ wte^T
__global__ void k_logits(const float* __restrict__ h1, const float* __restrict__ h2,
                         const float* __restrict__ g, const float* __restrict__ bt,
                         const float* __restrict__ wte, float* __restrict__ logits) {
    __shared__ float xl[8][768];
    __shared__ float mean[8], rstd[8];
    ln_stats(h1, h2, mean, rstd);
    __syncthreads();
    for (int i = threadIdx.x; i < 8 * 768; i += 256) {
        int b = i / 768, e = i % 768;
        xl[b][e] = (h1[i] + h2[i] - mean[b]) * rstd[b] * g[e] + bt[e];
    }
    __syncthreads();
    int t = threadIdx.x;
    int v = blockIdx.x * 64 + (t >> 2);
    if (v >= VV) return;
    int el = t & 3;
    const float4* w = (const float4*)(wte + (size_t)v * EE);
    float acc[8] = {0, 0, 0, 0, 0, 0, 0, 0};
    for (int i = el; i < 192; i += 4) {
        float4 w4 = w[i];
#pragma unroll
        for (int b = 0; b < 8; b++) {
            float4 xx = ((const float4*)xl[b])[i];
            acc[b] += w4.x * xx.x + w4.y * xx.y + w4.z * xx.z + w4.w * xx.w;
        }
    }
#pragma unroll
    for (int b = 0; b < 8; b++) {
        acc[b] += __shfl_xor(acc[b], 1);
        acc[b] += __shfl_xor(acc[b], 2);
    }
    if (el == 0) {
#pragma unroll
        for (int b = 0; b < 8; b++) logits[(size_t)b * VV + v] = acc[b];
    }
}

extern "C" void kernel_launch(void* const* d_in, const int* in_sizes, int n_in,
                              void* d_out, int out_size, void* d_ws, size_t ws_size,
                              hipStream_t stream) {
    const int* ids = (const int*)d_in[0];
    const int* posp = (const int*)d_in[1];
    const float* past_k = (const float*)d_in[2];
    const float* past_v = (const float*)d_in[3];
    const float* wte = (const float*)d_in[4];
    const float* wpe = (const float*)d_in[5];
    const float* ln1g = (const float*)d_in[6];
    const float* ln1b = (const float*)d_in[7];
    const float* aw = (const float*)d_in[8];
    const float* ab = (const float*)d_in[9];
    const float* pw = (const float*)d_in[10];
    const float* pb = (const float*)d_in[11];
    const float* ln2g = (const float*)d_in[12];
    const float* ln2b = (const float*)d_in[13];
    const float* fw = (const float*)d_in[14];
    const float* fb = (const float*)d_in[15];
    const float* fpw = (const float*)d_in[16];
    const float* fpb = (const float*)d_in[17];
    const float* lnfg = (const float*)d_in[18];
    const float* lnfb = (const float*)d_in[19];

    float* logits = (float*)d_out;
    float* okeys = logits + (size_t)BB * VV;
    float* ovals = okeys + (size_t)LL * BB * HH * SS * DD;

    float* ws = (float*)d_ws;
    float* hB = ws;                  // B*E
    float* hA = hB + BB * EE;        // B*E
    float* tmlp = hA + BB * EE;      // B*E
    float* tproj = tmlp + BB * EE;   // B*E
    float* qkv = tproj + BB * EE;    // B*3E
    float* fcbuf = qkv + BB * E3;    // B*4E
    float* pm = fcbuf + BB * E4;     // 96*NCH
    float* psum = pm + BB * HH * NCH;
    float* po = psum + BB * HH * NCH;  // 96*NCH*64

    const size_t n4 = (size_t)LL * BB * HH * SS * DD / 4;
    k_copy<<<2048, 256, 0, stream>>>((const float4*)past_k, (float4*)okeys, n4);
    k_copy<<<2048, 256, 0, stream>>>((const float4*)past_v, (float4*)ovals, n4);

    k_pre<<<120, 256, 0, stream>>>(ids, posp, wte, wpe, hB, tmlp, qkv, ab);

    for (int l = 0; l < LL; l++) {
        size_t co = (size_t)l * BB * HH * SS * DD;
        // x=LN1(hB+tmlp); qkv += x@aw ; writers: hA=hB+tmlp ; init: tproj=pb
        k_ln_gemm<<<24 * 36 + 24 + 24, 256, 0, stream>>>(
            hB, tmlp, ln1g + l * EE, ln1b + l * EE, aw + (size_t)l * EE * E3, qkv,
            E3, 36, hA, tproj, pb + (size_t)l * EE, EE);
        // attention partials (+ new K/V row) ; init: fcbuf=fb
        k_attn<<<BB * HH * NCH + 96, 256, 0, stream>>>(
            past_k + co, past_v + co, okeys + co, ovals + co,
            qkv, pm, psum, po, posp, fcbuf, fb + (size_t)l * E4);
        // tproj += combine(partials)@pw ; init: tmlp=fpb
        k_comb_gemm<<<24 * 12 + 24, 256, 0, stream>>>(
            pm, psum, po, pw + (size_t)l * EE * EE, tproj, tmlp, fpb + (size_t)l * EE);
        // x2=LN2(hA+tproj); fcbuf += x2@fw ; writers: hB=hA+tproj
        k_ln_gemm<<<24 * 48 + 24, 256, 0, stream>>>(
            hA, tproj, ln2g + l * EE, ln2b + l * EE, fw + (size_t)l * EE * E4, fcbuf,
            E4, 48, hB, nullptr, nullptr, 1);
        // tmlp += gelu(fcbuf)@fpw ; init (l<11): qkv=ab[l+1]
        int extra = (l < LL - 1) ? 72 : 0;
        k_gelu_gemm<<<96 * 12 + extra, 256, 0, stream>>>(
            fcbuf, fpw + (size_t)l * E4 * EE, tmlp, qkv, ab + (size_t)(l + 1) * E3);
    }
    // logits = lnf(hB+tmlp) @ wte^T
    k_logits<<<(VV + 63) / 64, 256, 0, stream>>>(hB, tmlp, lnfg, lnfb, wte, logits);
}

// Round 4
// 811.380 us; speedup vs baseline: 4.0910x; 1.1152x over previous
//
#include <hip/hip_runtime.h>
#include <hip/hip_bf16.h>

#define LL 12
#define BB 8
#define HH 12
#define EE 768
#define DD 64
#define SS 1024
#define VV 50257
#define E3 2304
#define E4 3072
#define NCH 16
#define CROWS 64
#define KCH 64

#define N4HALF 18874368ull              // float4 per KV buffer (L*B*H*S*D/4)
#define N4TOT  37748736ull              // both buffers
#define NSLICE 60
#define W4 ((N4TOT + NSLICE - 1) / NSLICE)
#define COPYBLK 512

__device__ __forceinline__ float gelu_tanh(float v) {
    float c = 0.7978845608028654f * (v + 0.044715f * v * v * v);
    return 0.5f * v * (1.0f + tanhf(c));
}

// copy one slice of the combined [K|V] cache space, skipping row==pos (attn writes it)
__device__ __forceinline__ void copy_slice(const float4* __restrict__ kq, const float4* __restrict__ vq,
                                           float4* __restrict__ ko, float4* __restrict__ vo,
                                           int pos, int slice, int blkLocal) {
    size_t base = (size_t)slice * W4;
    size_t end = base + W4;
    if (end > N4TOT) end = N4TOT;
    for (size_t i = base + (size_t)blkLocal * 256 + threadIdx.x; i < end; i += (size_t)COPYBLK * 256) {
        int row = (int)((i >> 4) & (SS - 1));
        if (row == pos) continue;
        if (i < N4HALF) ko[i] = kq[i];
        else { size_t j = i - N4HALF; vo[j] = vq[j]; }
    }
}

// prologue: embed -> hB, tmlp=0, qkv=attn bias layer0
__global__ void k_pre(const int* __restrict__ ids, const int* __restrict__ posp,
                      const float* __restrict__ wte, const float* __restrict__ wpe,
                      float* __restrict__ hB, float* __restrict__ tmlp,
                      float* __restrict__ qkv, const float* __restrict__ ab0) {
    int blk = blockIdx.x, t = threadIdx.x;
    if (blk < 24) {
        int i = blk * 256 + t;
        int b = i / EE, e = i % EE;
        hB[i] = wte[(size_t)ids[b] * EE + e] + wpe[(size_t)(*posp) * EE + e];
    } else if (blk < 48) {
        int i = (blk - 24) * 256 + t;
        tmlp[i] = 0.f;
    } else {
        int i = (blk - 48) * 256 + t;
        qkv[i] = ab0[i % E3];
    }
}

// per-row LN stats over (h1+h2): 8 rows x 32 lanes
__device__ __forceinline__ void ln_stats(const float* __restrict__ h1, const float* __restrict__ h2,
                                         float* mean, float* rstd) {
    int t = threadIdx.x, r = t >> 5, l = t & 31;
    float s = 0.f, ss = 0.f;
#pragma unroll
    for (int i = 0; i < 24; i++) {
        int e = l + i * 32;
        float v = h1[r * EE + e] + h2[r * EE + e];
        s += v; ss += v * v;
    }
#pragma unroll
    for (int m = 16; m >= 1; m >>= 1) { s += __shfl_xor(s, m); ss += __shfl_xor(ss, m); }
    if (l == 0) {
        float mu = s * (1.f / EE);
        mean[r] = mu;
        rstd[r] = rsqrtf(ss * (1.f / EE) - mu * mu + 1e-5f);
    }
}

// xl[8][64] x W[64 x 64cols] -> atomicAdd out[8][64cols]
__device__ __forceinline__ void gemm_tile(const float (*xl)[KCH], const float* __restrict__ W,
                                          float* __restrict__ out, int e0, int c0, int C) {
    int t = threadIdx.x;
    int c = c0 + (t & 63);
    int r2 = (t >> 6) * 2;
    const float* Wp = W + (size_t)e0 * C + c;
    float a0 = 0.f, a1 = 0.f;
#pragma unroll
    for (int e = 0; e < KCH; e++) {
        float w = Wp[(size_t)e * C];
        a0 += xl[r2][e] * w;
        a1 += xl[r2 + 1][e] * w;
    }
    atomicAdd(&out[(size_t)r2 * C + c], a0);
    atomicAdd(&out[(size_t)(r2 + 1) * C + c], a1);
}

// fused: x = LN(h1+h2); out += x @ W. extras: hWrite=h1+h2 (24), bias init (nBias), copy (COPYBLK)
__global__ void k_ln_gemm(const float* __restrict__ h1, const float* __restrict__ h2,
                          const float* __restrict__ g, const float* __restrict__ bt,
                          const float* __restrict__ W, float* __restrict__ out,
                          int C, int nColBlk,
                          float* __restrict__ hWrite,
                          float* __restrict__ ib, const float* __restrict__ bb, int bC, int nBias,
                          const float4* __restrict__ kq, const float4* __restrict__ vq,
                          float4* __restrict__ ko, float4* __restrict__ vo,
                          const int* __restrict__ posp, int slice) {
    int nMain = 12 * nColBlk;
    int blk = blockIdx.x, t = threadIdx.x;
    if (blk >= nMain) {
        int x = blk - nMain;
        if (x < 24) { int i = x * 256 + t; hWrite[i] = h1[i] + h2[i]; return; }
        x -= 24;
        if (x < nBias) { int i = x * 256 + t; ib[i] = bb[i % bC]; return; }
        copy_slice(kq, vq, ko, vo, *posp, slice, x - nBias);
        return;
    }
    int chunk = blk / nColBlk, colblk = blk % nColBlk;
    int e0 = chunk * KCH, c0 = colblk * 64;
    __shared__ float xl[8][KCH];
    __shared__ float mean[8], rstd[8];
    ln_stats(h1, h2, mean, rstd);
    __syncthreads();
    for (int i = t; i < 8 * KCH; i += 256) {
        int b = i >> 6, l = i & 63, e = e0 + l;
        xl[b][l] = (h1[b * EE + e] + h2[b * EE + e] - mean[b]) * rstd[b] * g[e] + bt[e];
    }
    __syncthreads();
    gemm_tile(xl, W, out, e0, c0, C);
}

// flash-decode attention chunk (+ write new K/V row). extras: fcbuf bias (96), copy
__global__ void k_attn(const float4* __restrict__ kq, const float4* __restrict__ vq,
                       float4* __restrict__ ko, float4* __restrict__ vo, size_t co,
                       const float* __restrict__ qkv,
                       float* __restrict__ pm, float* __restrict__ psum, float* __restrict__ po,
                       const int* __restrict__ posp,
                       float* __restrict__ ib, const float* __restrict__ bb, int slice) {
    const int NMAIN = BB * HH * NCH;
    int blk = blockIdx.x, t = threadIdx.x;
    if (blk >= NMAIN) {
        int x = blk - NMAIN;
        if (x < 96) { int i = x * 256 + t; ib[i] = bb[i % E4]; return; }
        copy_slice(kq, vq, ko, vo, *posp, slice, x - 96);
        return;
    }
    int ch = blk & (NCH - 1), bh = blk >> 4;
    int b = bh / HH, hh = bh % HH;
    int pos = *posp, kv = pos + 1;
    int j0 = ch * CROWS;
    int idx = bh * NCH + ch;
    if (j0 >= kv) { if (t == 0) psum[idx] = 0.f; return; }

    const size_t off = co + (size_t)bh * SS * DD;
    const float* Kc = (const float*)kq + off;
    const float* Vc = (const float*)vq + off;
    float* Ko = (float*)ko + off;
    float* Vo = (float*)vo + off;
    const float* qn = qkv + (size_t)b * E3 + hh * DD;
    const float* kn = qn + EE;
    const float* vn = qn + 2 * EE;

    __shared__ float qs[DD], s[CROWS], red[256], bc[2];
    if (t < DD) qs[t] = qn[t];
    __syncthreads();

    // K pass: 4 threads per row (16 floats each)
    int row = t >> 2, q = t & 3;
    int j = j0 + row;
    float sj = 0.f;
    if (j < kv) {
        const float4* s4 = (const float4*)(((j == pos) ? kn : (Kc + (size_t)j * DD)) + q * 16);
#pragma unroll
        for (int i = 0; i < 4; i++) {
            float4 k4 = s4[i];
            int e = q * 16 + 4 * i;
            sj += k4.x * qs[e] + k4.y * qs[e + 1] + k4.z * qs[e + 2] + k4.w * qs[e + 3];
        }
    }
    sj += __shfl_xor(sj, 1);
    sj += __shfl_xor(sj, 2);
    if (j == pos) {  // write new K row
        float4* dst = (float4*)(Ko + (size_t)pos * DD + q * 16);
        const float4* sn = (const float4*)(kn + q * 16);
#pragma unroll
        for (int i = 0; i < 4; i++) dst[i] = sn[i];
    }
    if (q == 0) s[row] = (j < kv) ? sj * 0.125f : -INFINITY;
    __syncthreads();

    if (t < 64) {
        float v = s[t];
#pragma unroll
        for (int m = 1; m <= 32; m <<= 1) v = fmaxf(v, __shfl_xor(v, m));
        if (t == 0) bc[0] = v;
    }
    __syncthreads();
    float m = bc[0];
    if (t < 64) s[t] = __expf(s[t] - m);
    __syncthreads();
    if (t < 64) {
        float p = s[t];
#pragma unroll
        for (int mm = 1; mm <= 32; mm <<= 1) p += __shfl_xor(p, mm);
        if (t == 0) bc[1] = p;
    }

    // V pass
    int d = t & 63, grp = t >> 6;
    float od = 0.f;
    for (int jj = j0 + grp; jj < j0 + CROWS; jj += 4) {
        if (jj == pos) {
            float vv = vn[d];
            Vo[(size_t)pos * DD + d] = vv;
            od += s[jj - j0] * vv;
        } else if (jj < kv) {
            od += s[jj - j0] * Vc[(size_t)jj * DD + d];
        }
    }
    __syncthreads();
    red[t] = od;
    __syncthreads();
    if (t < 64) {
        float tt = red[t] + red[64 + t] + red[128 + t] + red[192 + t];
        po[(size_t)idx * 64 + t] = tt;
    }
    if (t == 0) { pm[idx] = m; psum[idx] = bc[1]; }
}

// fused: o = combine(partials); tproj += o @ proj_w. extras: tmlp=fcp bias (24), copy
__global__ void k_comb_gemm(const float* __restrict__ pm, const float* __restrict__ psum,
                            const float* __restrict__ po,
                            const float* __restrict__ W, float* __restrict__ out,
                            float* __restrict__ ib, const float* __restrict__ bb,
                            const float4* __restrict__ kq, const float4* __restrict__ vq,
                            float4* __restrict__ ko, float4* __restrict__ vo,
                            const int* __restrict__ posp, int slice) {
    const int nMain = 12 * 12;
    int blk = blockIdx.x, t = threadIdx.x;
    if (blk >= nMain) {
        int x = blk - nMain;
        if (x < 24) { int i = x * 256 + t; ib[i] = bb[i % EE]; return; }
        copy_slice(kq, vq, ko, vo, *posp, slice, x - 24);
        return;
    }
    int chunk = blk / 12, colblk = blk % 12;
    int e0 = chunk * KCH, c0 = colblk * 64;
    __shared__ float xl[8][KCH];
    for (int i = t; i < 8 * KCH; i += 256) {
        int b = i >> 6, l = i & 63;
        int e = e0 + l;
        int hh = e >> 6, d = e & 63;
        int bh = b * HH + hh;
        float M = -INFINITY;
#pragma unroll
        for (int ch = 0; ch < NCH; ch++) {
            int idx = bh * NCH + ch;
            if (psum[idx] > 0.f) M = fmaxf(M, pm[idx]);
        }
        float den = 0.f, acc = 0.f;
#pragma unroll
        for (int ch = 0; ch < NCH; ch++) {
            int idx = bh * NCH + ch;
            float ps = psum[idx];
            if (ps > 0.f) {
                float f = __expf(pm[idx] - M);
                den += ps * f;
                acc += po[(size_t)idx * 64 + d] * f;
            }
        }
        xl[b][l] = acc / den;
    }
    __syncthreads();
    gemm_tile(xl, W, out, e0, c0, EE);
}

// fused: tmlp += gelu(fcbuf) @ fcp_w. extras: qkv = next-layer attn bias (nBias), copy
__global__ void k_gelu_gemm(const float* __restrict__ fc, const float* __restrict__ W,
                            float* __restrict__ out,
                            float* __restrict__ ib, const float* __restrict__ bb, int nBias,
                            const float4* __restrict__ kq, const float4* __restrict__ vq,
                            float4* __restrict__ ko, float4* __restrict__ vo,
                            const int* __restrict__ posp, int slice) {
    const int nMain = 48 * 12;
    int blk = blockIdx.x, t = threadIdx.x;
    if (blk >= nMain) {
        int x = blk - nMain;
        if (x < nBias) { int i = x * 256 + t; ib[i] = bb[i % E3]; return; }
        copy_slice(kq, vq, ko, vo, *posp, slice, x - nBias);
        return;
    }
    int chunk = blk / 12, colblk = blk % 12;
    int e0 = chunk * KCH, c0 = colblk * 64;
    __shared__ float xl[8][KCH];
    for (int i = t; i < 8 * KCH; i += 256) {
        int b = i >> 6, l = i & 63;
        xl[b][l] = gelu_tanh(fc[(size_t)b * E4 + e0 + l]);
    }
    __syncthreads();
    gemm_tile(xl, W, out, e0, c0, EE);
}

// fused final LN + logits = lnf(hB+tmlp) @ wte^T
__global__ void k_logits(const float* __restrict__ h1, const float* __restrict__ h2,
                         const float* __restrict__ g, const float* __restrict__ bt,
                         const float* __restrict__ wte, float* __restrict__ logits) {
    __shared__ float xl[8][768];
    __shared__ float mean[8], rstd[8];
    ln_stats(h1, h2, mean, rstd);
    __syncthreads();
    for (int i = threadIdx.x; i < 8 * 768; i += 256) {
        int b = i / 768, e = i % 768;
        xl[b][e] = (h1[i] + h2[i] - mean[b]) * rstd[b] * g[e] + bt[e];
    }
    __syncthreads();
    int t = threadIdx.x;
    int v = blockIdx.x * 64 + (t >> 2);
    if (v >= VV) return;
    int el = t & 3;
    const float4* w = (const float4*)(wte + (size_t)v * EE);
    float acc[8] = {0, 0, 0, 0, 0, 0, 0, 0};
    for (int i = el; i < 192; i += 4) {
        float4 w4 = w[i];
#pragma unroll
        for (int b = 0; b < 8; b++) {
            float4 xx = ((const float4*)xl[b])[i];
            acc[b] += w4.x * xx.x + w4.y * xx.y + w4.z * xx.z + w4.w * xx.w;
        }
    }
#pragma unroll
    for (int b = 0; b < 8; b++) {
        acc[b] += __shfl_xor(acc[b], 1);
        acc[b] += __shfl_xor(acc[b], 2);
    }
    if (el == 0) {
#pragma unroll
        for (int b = 0; b < 8; b++) logits[(size_t)b * VV + v] = acc[b];
    }
}

extern "C" void kernel_launch(void* const* d_in, const int* in_sizes, int n_in,
                              void* d_out, int out_size, void* d_ws, size_t ws_size,
                              hipStream_t stream) {
    const int* ids = (const int*)d_in[0];
    const int* posp = (const int*)d_in[1];
    const float4* past_k = (const float4*)d_in[2];
    const float4* past_v = (const float4*)d_in[3];
    const float* wte = (const float*)d_in[4];
    const float* wpe = (const float*)d_in[5];
    const float* ln1g = (const float*)d_in[6];
    const float* ln1b = (const float*)d_in[7];
    const float* aw = (const float*)d_in[8];
    const float* ab = (const float*)d_in[9];
    const float* pw = (const float*)d_in[10];
    const float* pb = (const float*)d_in[11];
    const float* ln2g = (const float*)d_in[12];
    const float* ln2b = (const float*)d_in[13];
    const float* fw = (const float*)d_in[14];
    const float* fb = (const float*)d_in[15];
    const float* fpw = (const float*)d_in[16];
    const float* fpb = (const float*)d_in[17];
    const float* lnfg = (const float*)d_in[18];
    const float* lnfb = (const float*)d_in[19];

    float* logits = (float*)d_out;
    float4* okeys = (float4*)(logits + (size_t)BB * VV);
    float4* ovals = okeys + N4HALF;

    float* ws = (float*)d_ws;
    float* hB = ws;
    float* hA = hB + BB * EE;
    float* tmlp = hA + BB * EE;
    float* tproj = tmlp + BB * EE;
    float* qkv = tproj + BB * EE;
    float* fcbuf = qkv + BB * E3;
    float* pm = fcbuf + BB * E4;
    float* psum = pm + BB * HH * NCH;
    float* po = psum + BB * HH * NCH;

    k_pre<<<120, 256, 0, stream>>>(ids, posp, wte, wpe, hB, tmlp, qkv, ab);

    for (int l = 0; l < LL; l++) {
        size_t co = (size_t)l * BB * HH * SS * DD;
        int sl = 5 * l;
        // x=LN1(hB+tmlp); qkv += x@aw ; hA=hB+tmlp ; tproj=pb ; copy slice
        k_ln_gemm<<<12 * 36 + 24 + 24 + COPYBLK, 256, 0, stream>>>(
            hB, tmlp, ln1g + l * EE, ln1b + l * EE, aw + (size_t)l * EE * E3, qkv,
            E3, 36, hA, tproj, pb + (size_t)l * EE, EE, 24,
            past_k, past_v, okeys, ovals, posp, sl + 0);
        // attention partials (+ new K/V row) ; fcbuf=fb ; copy slice
        k_attn<<<BB * HH * NCH + 96 + COPYBLK, 256, 0, stream>>>(
            past_k, past_v, okeys, ovals, co,
            qkv, pm, psum, po, posp, fcbuf, fb + (size_t)l * E4, sl + 1);
        // tproj += combine(partials)@pw ; tmlp=fpb ; copy slice
        k_comb_gemm<<<12 * 12 + 24 + COPYBLK, 256, 0, stream>>>(
            pm, psum, po, pw + (size_t)l * EE * EE, tproj, tmlp, fpb + (size_t)l * EE,
            past_k, past_v, okeys, ovals, posp, sl + 2);
        // x2=LN2(hA+tproj); fcbuf += x2@fw ; hB=hA+tproj ; copy slice
        k_ln_gemm<<<12 * 48 + 24 + 0 + COPYBLK, 256, 0, stream>>>(
            hA, tproj, ln2g + l * EE, ln2b + l * EE, fw + (size_t)l * EE * E4, fcbuf,
            E4, 48, hB, nullptr, nullptr, 1, 0,
            past_k, past_v, okeys, ovals, posp, sl + 3);
        // tmlp += gelu(fcbuf)@fpw ; qkv=ab[l+1] (if any) ; copy slice
        int nBias = (l < LL - 1) ? 72 : 0;
        k_gelu_gemm<<<48 * 12 + ((l < LL - 1) ? 72 : 0) + COPYBLK, 256, 0, stream>>>(
            fcbuf, fpw + (size_t)l * E4 * EE, tmlp, qkv, ab + (size_t)(l + 1) * E3, nBias,
            past_k, past_v, okeys, ovals, posp, sl + 4);
    }
    // logits = lnf(hB+tmlp) @ wte^T
    k_logits<<<(VV + 63) / 64, 256, 0, stream>>>(hB, tmlp, lnfg, lnfb, wte, logits);
}